// Round 6
// baseline (1424.549 us; speedup 1.0000x reference)
//
#include <hip/hip_runtime.h>

// ---------------- problem constants ----------------
#define V_CODES 8192
#define D_DIM   256
#define SPATIAL 4096            // 16*16*16
#define M_ROWS  32768           // 8 * 4096
#define NELEM   8388608         // M_ROWS * D_DIM

static constexpr float GAMMA_F = 0.99f;
static constexpr float OMG_F   = (float)(1.0 - 0.99);
static constexpr float EPS_F   = 1e-7f;
static constexpr float VEPS_F  = (float)(8192 * 1e-7);

// output layout (floats), concatenated in reference return order
static constexpr size_t OFF_QUANT = 0;            // 8388608  quant_st
static constexpr size_t OFF_IDX   = 8388608;      // 32768    enc_idx (stored as float)
static constexpr size_t OFF_QDIFF = 8421376;      // 1        quant_diff
static constexpr size_t OFF_NN    = 8421377;      // 8192     new_N
static constexpr size_t OFF_ZAVG  = 8429569;      // 2097152  new_z_avg
static constexpr size_t OFF_W     = 10526721;     // 2097152  new_weight

typedef _Float16 f16x8  __attribute__((ext_vector_type(8)));
typedef float    f32x4  __attribute__((ext_vector_type(4)));

// async global->LDS, 16B per lane; LDS dest is wave-uniform base + lane*16
#define GLL(gp, lp) __builtin_amdgcn_global_load_lds( \
    (const __attribute__((address_space(1))) unsigned int*)(gp), \
    (__attribute__((address_space(3))) unsigned int*)(lp), 16, 0, 0)

// ---------------- K0a: weight row norms (fp32) ----------------
__global__ void k_wnorm(const float* __restrict__ W, float* __restrict__ wnorm) {
    int v = blockIdx.x * 4 + (threadIdx.x >> 6);
    int lane = threadIdx.x & 63;
    float4 w4 = *(const float4*)(W + (size_t)v * D_DIM + lane * 4);
    float s = w4.x * w4.x + w4.y * w4.y + w4.z * w4.z + w4.w * w4.w;
    #pragma unroll
    for (int m = 32; m > 0; m >>= 1) s += __shfl_xor(s, m, 64);
    if (lane == 0) wnorm[v] = s;
}

// ---------------- K0c: split W (V x 256, k-contiguous) into fp16 hi/lo planes ----------------
__global__ void k_split_w(const float* __restrict__ W, _Float16* __restrict__ Wh,
                          _Float16* __restrict__ Wl) {
    size_t i8 = ((size_t)blockIdx.x * 256 + threadIdx.x) * 8;
    float4 a = *(const float4*)(W + i8);
    float4 b = *(const float4*)(W + i8 + 4);
    float v[8] = {a.x, a.y, a.z, a.w, b.x, b.y, b.z, b.w};
    f16x8 hi, lo;
    #pragma unroll
    for (int j = 0; j < 8; j++) {
        _Float16 h = (_Float16)v[j];
        hi[j] = h;
        lo[j] = (_Float16)(v[j] - (float)h);
    }
    *(f16x8*)(Wh + i8) = hi;
    *(f16x8*)(Wl + i8) = lo;
}

// ---------------- K0d: split + transpose X (b,k,sp) -> Xh/Xl (m, k) row-major ----------------
__global__ void k_split_x(const float* __restrict__ X, _Float16* __restrict__ Xh,
                          _Float16* __restrict__ Xl) {
    int bid  = blockIdx.x;            // 1024 blocks
    int lane = threadIdx.x & 63;
    int kg   = (bid & 1) * 4 + (threadIdx.x >> 6);   // 0..7 -> k base kg*32
    int m    = (bid >> 1) * 64 + lane;
    int b  = m >> 12;
    int sp = m & 4095;
    const float* src = X + (size_t)b * (D_DIM * SPATIAL) + (size_t)(kg * 32) * SPATIAL + sp;
    float v[32];
    #pragma unroll
    for (int j = 0; j < 32; j++) v[j] = src[(size_t)j * SPATIAL];   // coalesced across lanes
    _Float16* dh = Xh + (size_t)m * D_DIM + kg * 32;
    _Float16* dl = Xl + (size_t)m * D_DIM + kg * 32;
    #pragma unroll
    for (int c = 0; c < 4; c++) {
        f16x8 hi, lo;
        #pragma unroll
        for (int j = 0; j < 8; j++) {
            float x = v[c * 8 + j];
            _Float16 h = (_Float16)x;
            hi[j] = h;
            lo[j] = (_Float16)(x - (float)h);
        }
        *(f16x8*)(dh + c * 8) = hi;
        *(f16x8*)(dl + c * 8) = lo;
    }
}

// ---------------- K1: MFMA distance GEMM + argmin ----------------
// v7: EXACT round-0 structure (128x128 tile, 4 waves 2x2, 16x16x32 MFMA,
// single 32 KiB LDS buffer, two __syncthreads per K-step -- the proven-
// correct, best-measured variant at 623 us) with two additive costs removed:
//  (a) VALU-ectomy: K-loop fully unrolled; 8 global staging pointers hoisted
//      (per-step k advance +t*32 folds into the load immediate -- mechanism
//      proven correct & cheap in round 5); 16 LDS read addresses hoisted
//      (single buffer => loop-invariant). Per-step address VALU ~= 0.
//  (b) TLP: __launch_bounds__(256,4) -> 4 resident blocks/CU (VGPR 68,
//      LDS 32 KiB both allow it), doubling the pool that hides the per-step
//      GLL drain (m114 implicit wave-level overlap).
// LDS: 32 subtiles x 1 KiB, idx = wid*8+s (wid: 0=Xh 1=Xl 2=Wh 3=Wl).
// Fragment order: lane l <-> halves [8l,8l+8) = row (l&15), k-chunk (l>>4)
// -> linear GLL dest, conflict-free ds_read_b128. Math bit-identical to R0.
__device__ inline unsigned long long packkey(float s, int v) {
    unsigned u = __float_as_uint(s);
    u = (u & 0x80000000u) ? ~u : (u | 0x80000000u);
    return ((unsigned long long)u << 32) | (unsigned)v;
}

__global__ __launch_bounds__(256, 4) void k_mfma_argmin(
        const _Float16* __restrict__ Xh, const _Float16* __restrict__ Xl,
        const _Float16* __restrict__ Wh, const _Float16* __restrict__ Wl,
        const float* __restrict__ wnorm, unsigned long long* __restrict__ best) {
    __shared__ __align__(16) _Float16 lds[16384];   // 32 KiB, single buffer
    const int tid  = threadIdx.x;
    const int wid  = tid >> 6;
    const int lane = tid & 63;
    const int lrow = lane & 15, lq = lane >> 4;
    const int wy = wid >> 1, wx = wid & 1;
    const int m0 = blockIdx.y * 128;
    const int v0 = blockIdx.x * 128;

    // staging: wave wid owns plane wid, subtiles wid*8 .. wid*8+7
    const _Float16* const planes[4] = {Xh, Xl, Wh, Wl};
    const _Float16* const P = planes[wid];
    const int rowb = (wid < 2 ? m0 : v0) + lrow;

    // hoisted per-subtile global pointers (k=0); per-step +t*32 folds to imm
    const _Float16* gp[8];
    #pragma unroll
    for (int s = 0; s < 8; ++s)
        gp[s] = P + (size_t)(rowb + s * 16) * D_DIM + lq * 8;

    // hoisted loop-invariant LDS fragment read pointers
    const _Float16 *pah[4], *pal[4], *pbh[4], *pbl[4];
    #pragma unroll
    for (int i = 0; i < 4; ++i) {
        pah[i] = &lds[(      wy * 4 + i) * 512 + lane * 8];
        pal[i] = &lds[( 8 + wy * 4 + i) * 512 + lane * 8];
        pbh[i] = &lds[(16 + wx * 4 + i) * 512 + lane * 8];
        pbl[i] = &lds[(24 + wx * 4 + i) * 512 + lane * 8];
    }

    f32x4 acc[4][4] = {};

    #pragma unroll
    for (int t = 0; t < 8; ++t) {           // K-step: k0 = t*32 halves = t*64 B
        __syncthreads();                    // prior reads of lds done
        #pragma unroll
        for (int s = 0; s < 8; ++s)
            GLL(gp[s] + t * 32, &lds[(wid * 8 + s) * 512]);
        __syncthreads();                    // GLL writes visible
        f16x8 ah[4], al[4], bh[4], bl[4];
        #pragma unroll
        for (int i = 0; i < 4; ++i) {
            ah[i] = *(const f16x8*)pah[i];
            al[i] = *(const f16x8*)pal[i];
            bh[i] = *(const f16x8*)pbh[i];
            bl[i] = *(const f16x8*)pbl[i];
        }
        __builtin_amdgcn_s_setprio(1);
        #pragma unroll
        for (int mi = 0; mi < 4; ++mi)
            #pragma unroll
            for (int vi = 0; vi < 4; ++vi) {
                acc[mi][vi] = __builtin_amdgcn_mfma_f32_16x16x32_f16(ah[mi], bh[vi], acc[mi][vi], 0, 0, 0);
                acc[mi][vi] = __builtin_amdgcn_mfma_f32_16x16x32_f16(al[mi], bh[vi], acc[mi][vi], 0, 0, 0);
                acc[mi][vi] = __builtin_amdgcn_mfma_f32_16x16x32_f16(ah[mi], bl[vi], acc[mi][vi], 0, 0, 0);
            }
        __builtin_amdgcn_s_setprio(0);
    }

    float wnv[4];
    #pragma unroll
    for (int vi = 0; vi < 4; ++vi) wnv[vi] = wnorm[v0 + (wx * 4 + vi) * 16 + lrow];

    #pragma unroll
    for (int mi = 0; mi < 4; ++mi) {
        #pragma unroll
        for (int r = 0; r < 4; ++r) {
            unsigned long long k = ~0ull;
            #pragma unroll
            for (int vi = 0; vi < 4; ++vi) {
                int v = v0 + (wx * 4 + vi) * 16 + lrow;
                float s = wnv[vi] - 2.0f * acc[mi][vi][r];
                unsigned long long key = packkey(s, v);
                k = key < k ? key : k;
            }
            #pragma unroll
            for (int msk = 1; msk < 16; msk <<= 1) {
                unsigned long long o = __shfl_xor(k, msk, 64);
                k = o < k ? o : k;
            }
            if (lrow == 0) {
                int m = m0 + (wy * 4 + mi) * 16 + lq * 4 + r;
                atomicMin(&best[m], k);
            }
        }
    }
}

// ---------------- K2a: extract idx, count per code ----------------
__global__ void k_count(const unsigned long long* __restrict__ best,
                        int* __restrict__ counts, float* __restrict__ out) {
    int m = blockIdx.x * 256 + threadIdx.x;
    int v = (int)(unsigned)(best[m] & 0xFFFFFFFFull);
    atomicAdd(&counts[v], 1);
    out[OFF_IDX + m] = (float)v;
}

// ---------------- K2b: exclusive prefix over 8192 counts ----------------
__global__ void k_prefix(const int* __restrict__ counts, int* __restrict__ offsets,
                         int* __restrict__ cursor) {
    __shared__ int tsum[256];
    int t = threadIdx.x;
    int local[32];
    int s = 0;
    #pragma unroll
    for (int i = 0; i < 32; i++) { local[i] = s; s += counts[t * 32 + i]; }
    tsum[t] = s;
    __syncthreads();
    if (t == 0) {
        int run = 0;
        for (int i = 0; i < 256; i++) { int c = tsum[i]; tsum[i] = run; run += c; }
    }
    __syncthreads();
    int base = tsum[t];
    #pragma unroll
    for (int i = 0; i < 32; i++) {
        int o = base + local[i];
        offsets[t * 32 + i] = o;
        cursor[t * 32 + i]  = o;
    }
}

// ---------------- K2c: fill bins ----------------
__global__ void k_fill(const unsigned long long* __restrict__ best,
                       int* __restrict__ cursor, int* __restrict__ bin) {
    int m = blockIdx.x * 256 + threadIdx.x;
    int v = (int)(unsigned)(best[m] & 0xFFFFFFFFull);
    int pos = atomicAdd(&cursor[v], 1);
    bin[pos] = m;
}

// ---------------- K2d: per-code reduction -> new_N, new_z_avg (no atomics) ----------------
__global__ void k_codes(const _Float16* __restrict__ Xh, const _Float16* __restrict__ Xl,
                        const float* __restrict__ N, const float* __restrict__ zavg,
                        const int* __restrict__ counts, const int* __restrict__ offsets,
                        const int* __restrict__ bin, float* __restrict__ out) {
    int v = blockIdx.x;
    int d = threadIdx.x;
    int cnt = counts[v];
    int off = offsets[v];
    float s = 0.0f;
    for (int r = 0; r < cnt; r++) {
        int m = bin[off + r];
        s += (float)Xh[(size_t)m * D_DIM + d] + (float)Xl[(size_t)m * D_DIM + d];
    }
    out[OFF_ZAVG + (size_t)v * D_DIM + d] = GAMMA_F * zavg[(size_t)v * D_DIM + d] + OMG_F * s;
    if (d == 0) out[OFF_NN + v] = GAMMA_F * N[v] + OMG_F * (float)cnt;
}

// ---------------- K3: quant_st + quant_diff (float4 along sp) ----------------
__global__ void k_quant(const float* __restrict__ X, const float* __restrict__ W,
                        const unsigned long long* __restrict__ best, float* __restrict__ out,
                        float* __restrict__ ws_scal) {
    int e4 = blockIdx.x * 256 + threadIdx.x;    // element/4 in (b, d, sp) order
    int e  = e4 * 4;
    int sp = e & 4095;
    int bd = e >> 12;
    int d  = bd & 255;
    int b  = bd >> 8;
    int mb = b * SPATIAL + sp;
    float4 x4 = *(const float4*)(X + e);
    float q[4];
    float p = 0.0f;
    #pragma unroll
    for (int j = 0; j < 4; j++) {
        int v = (int)(unsigned)(best[mb + j] & 0xFFFFFFFFull);
        float wv = W[(size_t)v * D_DIM + d];
        float xv = (j == 0) ? x4.x : (j == 1) ? x4.y : (j == 2) ? x4.z : x4.w;
        q[j] = (wv - xv) + xv;                 // straight-through
        float df = xv - wv;
        p = fmaf(df, df, p);
    }
    *(float4*)(out + OFF_QUANT + e) = make_float4(q[0], q[1], q[2], q[3]);
    // block-reduce p -> one atomic
    #pragma unroll
    for (int msk = 32; msk > 0; msk >>= 1) p += __shfl_xor(p, msk, 64);
    __shared__ float red[4];
    int lane = threadIdx.x & 63, w = threadIdx.x >> 6;
    if (lane == 0) red[w] = p;
    __syncthreads();
    if (threadIdx.x == 0)
        atomicAdd(ws_scal, red[0] + red[1] + red[2] + red[3]);
}

// ---------------- K4a: n = sum(new_N); finalize quant_diff ----------------
__global__ void k_finalize_n(const float* __restrict__ outNN, float* __restrict__ ws_scal,
                             float* __restrict__ out_qdiff) {
    __shared__ float red[256];
    float s = 0.0f;
    for (int v = threadIdx.x; v < V_CODES; v += 256) s += outNN[v];
    red[threadIdx.x] = s;
    __syncthreads();
    #pragma unroll
    for (int t = 128; t > 0; t >>= 1) {
        if (threadIdx.x < t) red[threadIdx.x] += red[threadIdx.x + t];
        __syncthreads();
    }
    if (threadIdx.x == 0) {
        ws_scal[1] = red[0];
        out_qdiff[0] = ws_scal[0] * (1.0f / 8388608.0f);
    }
}

// ---------------- K4b: new_weight = new_z_avg / w ----------------
__global__ void k_weight(const float* __restrict__ zavg_out, const float* __restrict__ nn_out,
                         const float* __restrict__ ws_scal, float* __restrict__ out_w) {
    int i = blockIdx.x * 256 + threadIdx.x;
    int v = i >> 8;
    float n = ws_scal[1];
    float w = (nn_out[v] + EPS_F) / (n + VEPS_F) * n;
    out_w[i] = zavg_out[i] / w;
}

extern "C" void kernel_launch(void* const* d_in, const int* in_sizes, int n_in,
                              void* d_out, int out_size, void* d_ws, size_t ws_size,
                              hipStream_t stream) {
    const float* x    = (const float*)d_in[0];
    const float* w    = (const float*)d_in[1];
    const float* N    = (const float*)d_in[2];
    const float* zavg = (const float*)d_in[3];
    float* out = (float*)d_out;
    char*  wsb = (char*)d_ws;

    // workspace layout (bytes)
    float* ws_scal   = (float*)wsb;                      // 64 B   [0]=qdiff sum [1]=n
    int*   ws_counts = (int*)(wsb + 64);                 // 32 KB
    float* ws_wnorm  = (float*)(wsb + 32832);            // 32 KB
    int*   ws_off    = (int*)(wsb + 65600);              // 32 KB
    int*   ws_cur    = (int*)(wsb + 98368);              // 32 KB
    int*   ws_bin    = (int*)(wsb + 131136);             // 128 KB
    unsigned long long* ws_best = (unsigned long long*)(wsb + 262208);  // 256 KB
    _Float16* Xh = (_Float16*)(wsb + 524352);            // 16.78 MB
    _Float16* Xl = (_Float16*)(wsb + 524352 + 16777216);
    _Float16* Wh = (_Float16*)(wsb + 524352 + 2 * 16777216);  // 4.19 MB
    _Float16* Wl = (_Float16*)(wsb + 524352 + 2 * 16777216 + 4194304);
    // total ~42.5 MB

    hipMemsetAsync(wsb, 0, 32832, stream);                       // scal + counts
    hipMemsetAsync(ws_best, 0xFF, (size_t)M_ROWS * 8, stream);

    k_wnorm  <<<V_CODES / 4, 256, 0, stream>>>(w, ws_wnorm);
    k_split_w<<<(V_CODES * D_DIM) / (256 * 8), 256, 0, stream>>>(w, Wh, Wl);
    k_split_x<<<1024, 256, 0, stream>>>(x, Xh, Xl);

    dim3 grid(V_CODES / 128, M_ROWS / 128);
    k_mfma_argmin<<<grid, 256, 0, stream>>>(Xh, Xl, Wh, Wl, ws_wnorm, ws_best);

    k_count  <<<M_ROWS / 256, 256, 0, stream>>>(ws_best, ws_counts, out);
    k_prefix <<<1, 256, 0, stream>>>(ws_counts, ws_off, ws_cur);
    k_fill   <<<M_ROWS / 256, 256, 0, stream>>>(ws_best, ws_cur, ws_bin);
    k_codes  <<<V_CODES, 256, 0, stream>>>(Xh, Xl, N, zavg, ws_counts, ws_off, ws_bin, out);
    k_quant  <<<NELEM / (256 * 4), 256, 0, stream>>>(x, w, ws_best, out, ws_scal);

    k_finalize_n<<<1, 256, 0, stream>>>(out + OFF_NN, ws_scal, out + OFF_QDIFF);
    k_weight <<<(V_CODES * D_DIM) / 256, 256, 0, stream>>>(out + OFF_ZAVG, out + OFF_NN, ws_scal, out + OFF_W);
}

// Round 7
// 879.079 us; speedup vs baseline: 1.6205x; 1.6205x over previous
//
#include <hip/hip_runtime.h>

// ---------------- problem constants ----------------
#define V_CODES 8192
#define D_DIM   256
#define SPATIAL 4096            // 16*16*16
#define M_ROWS  32768           // 8 * 4096
#define NELEM   8388608         // M_ROWS * D_DIM

static constexpr float GAMMA_F = 0.99f;
static constexpr float OMG_F   = (float)(1.0 - 0.99);
static constexpr float EPS_F   = 1e-7f;
static constexpr float VEPS_F  = (float)(8192 * 1e-7);

// output layout (floats), concatenated in reference return order
static constexpr size_t OFF_QUANT = 0;            // 8388608  quant_st
static constexpr size_t OFF_IDX   = 8388608;      // 32768    enc_idx (stored as float)
static constexpr size_t OFF_QDIFF = 8421376;      // 1        quant_diff
static constexpr size_t OFF_NN    = 8421377;      // 8192     new_N
static constexpr size_t OFF_ZAVG  = 8429569;      // 2097152  new_z_avg
static constexpr size_t OFF_W     = 10526721;     // 2097152  new_weight

typedef _Float16 f16x8  __attribute__((ext_vector_type(8)));
typedef _Float16 f16x4  __attribute__((ext_vector_type(4)));
typedef float    f32x4  __attribute__((ext_vector_type(4)));

// async global->LDS, 16B per lane; LDS dest is wave-uniform base + lane*16
#define GLL(gp, lp) __builtin_amdgcn_global_load_lds( \
    (const __attribute__((address_space(1))) unsigned int*)(gp), \
    (__attribute__((address_space(3))) unsigned int*)(lp), 16, 0, 0)

// ---------------- K0c: split W into fp16 hi/lo planes + row norms (fused) ----------------
__global__ void k_split_w(const float* __restrict__ W, _Float16* __restrict__ Wh,
                          _Float16* __restrict__ Wl, float* __restrict__ wnorm) {
    int t = threadIdx.x;
    size_t i8 = ((size_t)blockIdx.x * 256 + t) * 8;
    float4 a = *(const float4*)(W + i8);
    float4 b = *(const float4*)(W + i8 + 4);
    float v[8] = {a.x, a.y, a.z, a.w, b.x, b.y, b.z, b.w};
    f16x8 hi, lo;
    float ns = 0.0f;
    #pragma unroll
    for (int j = 0; j < 8; j++) {
        _Float16 h = (_Float16)v[j];
        hi[j] = h;
        lo[j] = (_Float16)(v[j] - (float)h);
        ns = fmaf(v[j], v[j], ns);
    }
    *(f16x8*)(Wh + i8) = hi;
    *(f16x8*)(Wl + i8) = lo;
    // row norm: 32 threads per 256-elem row (8 elems each); reduce in 32-group
    #pragma unroll
    for (int m = 16; m > 0; m >>= 1) ns += __shfl_xor(ns, m, 64);
    if ((t & 31) == 0) wnorm[blockIdx.x * 8 + (t >> 5)] = ns;
}

// ---------------- K0d: split + transpose X (b,k,sp) -> Xh/Xl (m, k) row-major ----------------
__global__ void k_split_x(const float* __restrict__ X, _Float16* __restrict__ Xh,
                          _Float16* __restrict__ Xl) {
    int bid  = blockIdx.x;            // 1024 blocks
    int lane = threadIdx.x & 63;
    int kg   = (bid & 1) * 4 + (threadIdx.x >> 6);   // 0..7 -> k base kg*32
    int m    = (bid >> 1) * 64 + lane;
    int b  = m >> 12;
    int sp = m & 4095;
    const float* src = X + (size_t)b * (D_DIM * SPATIAL) + (size_t)(kg * 32) * SPATIAL + sp;
    float v[32];
    #pragma unroll
    for (int j = 0; j < 32; j++) v[j] = src[(size_t)j * SPATIAL];   // coalesced across lanes
    _Float16* dh = Xh + (size_t)m * D_DIM + kg * 32;
    _Float16* dl = Xl + (size_t)m * D_DIM + kg * 32;
    #pragma unroll
    for (int c = 0; c < 4; c++) {
        f16x8 hi, lo;
        #pragma unroll
        for (int j = 0; j < 8; j++) {
            float x = v[c * 8 + j];
            _Float16 h = (_Float16)x;
            hi[j] = h;
            lo[j] = (_Float16)(x - (float)h);
        }
        *(f16x8*)(dh + c * 8) = hi;
        *(f16x8*)(dl + c * 8) = lo;
    }
}

// ---------------- K1: MFMA distance GEMM + argmin ----------------
// v8: R0's proven schedule (single-buffer, 2x __syncthreads per K-step,
// 16x16x32, same fragment math / product order / epilogue) with the tile
// widened to 128x256 (BM x BN), 4 waves (2x2, each 64x128 out):
//  - 8192 blocks (was 16384): per-block fixed costs (prologue drain,
//    epilogue argmin) halve -- K=256 gives only 8 K-steps to amortize them.
//  - staging 4.2 -> 3.2 GB; LDS reads/FLOP -25% (24 reads per 96 MFMA).
//  - acc[4][8] = 128 regs; B-frags consumed in quarters (16 live) to stay
//    under the 256-reg tier (2 waves/SIMD, 2 blocks/CU -- same as R0).
// LDS: 48 subtiles x 1 KiB: Xh 0-7, Xl 8-15, Wh 16-31, Wl 32-47.
// Subtile fragment order: lane l <-> halves [8l,8l+8) = row (l&15),
// k-chunk (l>>4) -> linear GLL dest, conflict-free ds_read_b128.
__device__ inline unsigned long long packkey(float s, int v) {
    unsigned u = __float_as_uint(s);
    u = (u & 0x80000000u) ? ~u : (u | 0x80000000u);
    return ((unsigned long long)u << 32) | (unsigned)v;
}

__global__ __launch_bounds__(256, 2) void k_mfma_argmin(
        const _Float16* __restrict__ Xh, const _Float16* __restrict__ Xl,
        const _Float16* __restrict__ Wh, const _Float16* __restrict__ Wl,
        const float* __restrict__ wnorm, unsigned long long* __restrict__ best) {
    __shared__ __align__(16) _Float16 lds[24576];   // 48 KiB, single buffer
    const int tid  = threadIdx.x;
    const int wid  = tid >> 6;
    const int lane = tid & 63;
    const int lrow = lane & 15, lq = lane >> 4;
    const int wy = wid >> 1, wx = wid & 1;          // wave out: rows [wy*64,+64), cols [wx*128,+128)
    const int m0 = blockIdx.y * 128;
    const int v0 = blockIdx.x * 256;

    const _Float16* const planes[4] = {Xh, Xl, Wh, Wl};

    // staging: wave wid owns subtiles ss = wid*12 .. wid*12+11
    const _Float16* gp[12];
    #pragma unroll
    for (int j = 0; j < 12; ++j) {
        int ss = wid * 12 + j;
        int pl = (ss >= 8) + (ss >= 16) + (ss >= 32);
        int ro = ss - (pl == 1 ? 8 : pl == 2 ? 16 : pl == 3 ? 32 : 0);
        gp[j] = planes[pl] + (size_t)((pl < 2 ? m0 : v0) + ro * 16 + lrow) * D_DIM + lq * 8;
    }

    f32x4 acc[4][8] = {};

    for (int k0 = 0; k0 < D_DIM; k0 += 32) {
        __syncthreads();                            // prior LDS reads done
        #pragma unroll
        for (int j = 0; j < 12; ++j)
            GLL(gp[j] + k0, &lds[(wid * 12 + j) * 512]);
        __syncthreads();                            // GLL writes visible
        f16x8 ah[4], al[4];
        #pragma unroll
        for (int i = 0; i < 4; ++i) {
            ah[i] = *(const f16x8*)&lds[(     wy * 4 + i) * 512 + lane * 8];
            al[i] = *(const f16x8*)&lds[(8 +  wy * 4 + i) * 512 + lane * 8];
        }
        #pragma unroll
        for (int h = 0; h < 4; ++h) {               // vi quarter: vi = h*2+vj
            f16x8 bh[2], bl[2];
            #pragma unroll
            for (int i = 0; i < 2; ++i) {
                bh[i] = *(const f16x8*)&lds[(16 + wx * 8 + h * 2 + i) * 512 + lane * 8];
                bl[i] = *(const f16x8*)&lds[(32 + wx * 8 + h * 2 + i) * 512 + lane * 8];
            }
            __builtin_amdgcn_s_setprio(1);
            #pragma unroll
            for (int mi = 0; mi < 4; ++mi)
                #pragma unroll
                for (int vj = 0; vj < 2; ++vj) {
                    acc[mi][h*2+vj] = __builtin_amdgcn_mfma_f32_16x16x32_f16(ah[mi], bh[vj], acc[mi][h*2+vj], 0, 0, 0);
                    acc[mi][h*2+vj] = __builtin_amdgcn_mfma_f32_16x16x32_f16(al[mi], bh[vj], acc[mi][h*2+vj], 0, 0, 0);
                    acc[mi][h*2+vj] = __builtin_amdgcn_mfma_f32_16x16x32_f16(ah[mi], bl[vj], acc[mi][h*2+vj], 0, 0, 0);
                }
            __builtin_amdgcn_s_setprio(0);
        }
    }

    float wnv[8];
    #pragma unroll
    for (int vi = 0; vi < 8; ++vi) wnv[vi] = wnorm[v0 + (wx * 8 + vi) * 16 + lrow];

    #pragma unroll
    for (int mi = 0; mi < 4; ++mi) {
        #pragma unroll
        for (int r = 0; r < 4; ++r) {
            unsigned long long k = ~0ull;
            #pragma unroll
            for (int vi = 0; vi < 8; ++vi) {
                int v = v0 + (wx * 8 + vi) * 16 + lrow;
                float s = wnv[vi] - 2.0f * acc[mi][vi][r];
                unsigned long long key = packkey(s, v);
                k = key < k ? key : k;
            }
            #pragma unroll
            for (int msk = 1; msk < 16; msk <<= 1) {
                unsigned long long o = __shfl_xor(k, msk, 64);
                k = o < k ? o : k;
            }
            if (lrow == 0) {
                int m = m0 + (wy * 4 + mi) * 16 + lq * 4 + r;
                atomicMin(&best[m], k);
            }
        }
    }
}

// ---------------- K2a: extract idx, count per code ----------------
__global__ void k_count(const unsigned long long* __restrict__ best,
                        int* __restrict__ counts, float* __restrict__ out) {
    int m = blockIdx.x * 256 + threadIdx.x;
    int v = (int)(unsigned)(best[m] & 0xFFFFFFFFull);
    atomicAdd(&counts[v], 1);
    out[OFF_IDX + m] = (float)v;
}

// ---------------- K2b: exclusive prefix over 8192 counts ----------------
__global__ void k_prefix(const int* __restrict__ counts, int* __restrict__ offsets,
                         int* __restrict__ cursor) {
    __shared__ int tsum[256];
    int t = threadIdx.x;
    int local[32];
    int s = 0;
    #pragma unroll
    for (int i = 0; i < 32; i++) { local[i] = s; s += counts[t * 32 + i]; }
    tsum[t] = s;
    __syncthreads();
    if (t == 0) {
        int run = 0;
        for (int i = 0; i < 256; i++) { int c = tsum[i]; tsum[i] = run; run += c; }
    }
    __syncthreads();
    int base = tsum[t];
    #pragma unroll
    for (int i = 0; i < 32; i++) {
        int o = base + local[i];
        offsets[t * 32 + i] = o;
        cursor[t * 32 + i]  = o;
    }
}

// ---------------- K2c: fill bins ----------------
__global__ void k_fill(const unsigned long long* __restrict__ best,
                       int* __restrict__ cursor, int* __restrict__ bin) {
    int m = blockIdx.x * 256 + threadIdx.x;
    int v = (int)(unsigned)(best[m] & 0xFFFFFFFFull);
    int pos = atomicAdd(&cursor[v], 1);
    bin[pos] = m;
}

// ---------------- K2d: per-code reduction -> new_N, new_z_avg ----------------
// v8: vectorized (8-B f16x4 loads per plane) + 4 rows in flight per block;
// also accumulates n = sum(new_N) via one atomicAdd per code (replaces
// k_finalize_n's reduction).
__global__ void k_codes(const _Float16* __restrict__ Xh, const _Float16* __restrict__ Xl,
                        const float* __restrict__ N, const float* __restrict__ zavg,
                        const int* __restrict__ counts, const int* __restrict__ offsets,
                        const int* __restrict__ bin, float* __restrict__ out,
                        float* __restrict__ ws_scal) {
    int v = blockIdx.x;
    int t = threadIdx.x;
    int r4 = t >> 6;          // row class 0..3
    int dg = t & 63;          // d-group: d = dg*4 .. dg*4+3
    int cnt = counts[v];
    int off = offsets[v];
    float s0 = 0.f, s1 = 0.f, s2 = 0.f, s3 = 0.f;
    for (int r = r4; r < cnt; r += 4) {
        int m = bin[off + r];
        f16x4 h = *(const f16x4*)(Xh + (size_t)m * D_DIM + dg * 4);
        f16x4 l = *(const f16x4*)(Xl + (size_t)m * D_DIM + dg * 4);
        s0 += (float)h[0] + (float)l[0];
        s1 += (float)h[1] + (float)l[1];
        s2 += (float)h[2] + (float)l[2];
        s3 += (float)h[3] + (float)l[3];
    }
    __shared__ float red[4][256];
    *(float4*)&red[r4][dg * 4] = make_float4(s0, s1, s2, s3);
    __syncthreads();
    float tot = red[0][t] + red[1][t] + red[2][t] + red[3][t];
    out[OFF_ZAVG + (size_t)v * D_DIM + t] = GAMMA_F * zavg[(size_t)v * D_DIM + t] + OMG_F * tot;
    if (t == 0) {
        float nn = GAMMA_F * N[v] + OMG_F * (float)cnt;
        out[OFF_NN + v] = nn;
        atomicAdd(&ws_scal[1], nn);
    }
}

// ---------------- K3: quant_st + quant_diff (float4 along sp) ----------------
__global__ void k_quant(const float* __restrict__ X, const float* __restrict__ W,
                        const unsigned long long* __restrict__ best, float* __restrict__ out,
                        float* __restrict__ ws_scal) {
    int e4 = blockIdx.x * 256 + threadIdx.x;    // element/4 in (b, d, sp) order
    int e  = e4 * 4;
    int sp = e & 4095;
    int bd = e >> 12;
    int d  = bd & 255;
    int b  = bd >> 8;
    int mb = b * SPATIAL + sp;
    float4 x4 = *(const float4*)(X + e);
    float q[4];
    float p = 0.0f;
    #pragma unroll
    for (int j = 0; j < 4; j++) {
        int v = (int)(unsigned)(best[mb + j] & 0xFFFFFFFFull);
        float wv = W[(size_t)v * D_DIM + d];
        float xv = (j == 0) ? x4.x : (j == 1) ? x4.y : (j == 2) ? x4.z : x4.w;
        q[j] = (wv - xv) + xv;                 // straight-through
        float df = xv - wv;
        p = fmaf(df, df, p);
    }
    *(float4*)(out + OFF_QUANT + e) = make_float4(q[0], q[1], q[2], q[3]);
    // block-reduce p -> one atomic
    #pragma unroll
    for (int msk = 32; msk > 0; msk >>= 1) p += __shfl_xor(p, msk, 64);
    __shared__ float red[4];
    int lane = threadIdx.x & 63, w = threadIdx.x >> 6;
    if (lane == 0) red[w] = p;
    __syncthreads();
    if (threadIdx.x == 0)
        atomicAdd(ws_scal, red[0] + red[1] + red[2] + red[3]);
}

// ---------------- K4: new_weight = new_z_avg / w ; finalize quant_diff ----------------
__global__ void k_weight(const float* __restrict__ zavg_out, const float* __restrict__ nn_out,
                         const float* __restrict__ ws_scal, float* __restrict__ out_w,
                         float* __restrict__ out_qdiff) {
    int i = blockIdx.x * 256 + threadIdx.x;
    if (i == 0) out_qdiff[0] = ws_scal[0] * (1.0f / 8388608.0f);
    int v = i >> 8;
    float n = ws_scal[1];
    float w = (nn_out[v] + EPS_F) / (n + VEPS_F) * n;
    out_w[i] = zavg_out[i] / w;
}

extern "C" void kernel_launch(void* const* d_in, const int* in_sizes, int n_in,
                              void* d_out, int out_size, void* d_ws, size_t ws_size,
                              hipStream_t stream) {
    const float* x    = (const float*)d_in[0];
    const float* w    = (const float*)d_in[1];
    const float* N    = (const float*)d_in[2];
    const float* zavg = (const float*)d_in[3];
    float* out = (float*)d_out;
    char*  wsb = (char*)d_ws;

    // workspace layout (bytes)
    float* ws_scal   = (float*)wsb;                      // 64 B   [0]=qdiff sum [1]=n
    int*   ws_counts = (int*)(wsb + 64);                 // 32 KB
    float* ws_wnorm  = (float*)(wsb + 32832);            // 32 KB
    int*   ws_off    = (int*)(wsb + 65600);              // 32 KB
    int*   ws_cur    = (int*)(wsb + 98368);              // 32 KB
    int*   ws_bin    = (int*)(wsb + 131136);             // 128 KB
    unsigned long long* ws_best = (unsigned long long*)(wsb + 262208);  // 256 KB
    _Float16* Xh = (_Float16*)(wsb + 524352);            // 16.78 MB
    _Float16* Xl = (_Float16*)(wsb + 524352 + 16777216);
    _Float16* Wh = (_Float16*)(wsb + 524352 + 2 * 16777216);  // 4.19 MB
    _Float16* Wl = (_Float16*)(wsb + 524352 + 2 * 16777216 + 4194304);
    // total ~42.5 MB

    hipMemsetAsync(wsb, 0, 32832, stream);                       // scal + counts
    hipMemsetAsync(ws_best, 0xFF, (size_t)M_ROWS * 8, stream);

    k_split_w<<<(V_CODES * D_DIM) / (256 * 8), 256, 0, stream>>>(w, Wh, Wl, ws_wnorm);
    k_split_x<<<1024, 256, 0, stream>>>(x, Xh, Xl);

    dim3 grid(V_CODES / 256, M_ROWS / 128);
    k_mfma_argmin<<<grid, 256, 0, stream>>>(Xh, Xl, Wh, Wl, ws_wnorm, ws_best);

    k_count  <<<M_ROWS / 256, 256, 0, stream>>>(ws_best, ws_counts, out);
    k_prefix <<<1, 256, 0, stream>>>(ws_counts, ws_off, ws_cur);
    k_fill   <<<M_ROWS / 256, 256, 0, stream>>>(ws_best, ws_cur, ws_bin);
    k_codes  <<<V_CODES, 256, 0, stream>>>(Xh, Xl, N, zavg, ws_counts, ws_off, ws_bin, out, ws_scal);
    k_quant  <<<NELEM / (256 * 4), 256, 0, stream>>>(x, w, ws_best, out, ws_scal);

    k_weight <<<(V_CODES * D_DIM) / 256, 256, 0, stream>>>(out + OFF_ZAVG, out + OFF_NN, ws_scal,
                                                           out + OFF_W, out + OFF_QDIFF);
}